// Round 1
// 342.443 us; speedup vs baseline: 1.0061x; 1.0061x over previous
//
#include <hip/hip_runtime.h>

// FlattenHead: compact valid rows of x[B,T,D] (fp32) into out, where row (b,t)
// is valid iff t < seq_lens[b]. out[prefix[b]+t, :] = x[b, t, :].
// Pure memory-bound row gather: 134 MB read + 134 MB write at B=16,T=4096,D=1024.
//
// V2 design vs V1 (one block per row, separate prefix kernel, ~2.5 TB/s):
//  - single fused kernel: prefix scan of seq_lens (B=16) done per-block into
//    wave-uniform registers (SGPRs) -- removes the prefix_kernel launch and the
//    per-block global prefix[] reads from the critical path. No workspace.
//  - persistent grid-stride blocks, 8 rows per iteration: 8 independent float4
//    loads in flight per thread (ILP=8) instead of 1 load->store->endpgm.
//    32 KB contiguous read + 32 KB contiguous write per block iteration.
//  - batch lookup = fully unrolled compare/select chain on register-resident
//    thresholds (static indexing only -> no scratch, no LDS traffic):
//      src_row = r + corr,  corr = b*TT - prefix[b],  b = max{i: prefix[i]<=r}
//  - nontemporal load/store on the bulk path (streaming, zero reuse).

#define DD 1024   // floats per row
#define TT 4096   // rows per batch
#define F4 256    // float4s per row (DD/4)
#define NB 16     // specialized batch count

typedef float f4 __attribute__((ext_vector_type(4)));

// ---------------------------------------------------------------------------
// Specialized kernel: n_b == 16.
__global__ __launch_bounds__(256) void gather16(
        const float* __restrict__ x, const void* __restrict__ seq_raw,
        float* __restrict__ out, int total_rows) {
    const int tid = threadIdx.x;

    // ---- dtype defense + prefix scan (uniform across the wave -> SGPRs) ----
    // Harness may hand int32 or int64 seq_lens; pick whichever view's total
    // matches total_rows (= out_size / D). Reading s32[0..15] is 64 B, safe
    // under both layouts.
    const int*       s32 = (const int*)seq_raw;
    const long long* s64 = (const long long*)seq_raw;
    long long sum32 = 0;
#pragma unroll
    for (int i = 0; i < NB; ++i) sum32 += (long long)s32[i];
    const bool use32 = (sum32 == (long long)total_rows);

    int preA[NB];   // preA[i] = exclusive prefix (first row index of batch i)
    int cA[NB];     // cA[i]   = i*TT - preA[i]   (src-row correction)
    int acc = 0;
    if (use32) {
#pragma unroll
        for (int i = 0; i < NB; ++i) {
            preA[i] = acc; cA[i] = i * TT - acc; acc += s32[i];
        }
    } else {
#pragma unroll
        for (int i = 0; i < NB; ++i) {
            preA[i] = acc; cA[i] = i * TT - acc; acc += (int)s64[i];
        }
    }

    const f4* __restrict__ x4 = (const f4*)x;
    f4* __restrict__ o4       = (f4*)out;

    // ---- persistent grid-stride over groups of 8 rows ----
    const int nG = (total_rows + 7) >> 3;
    for (int g = blockIdx.x; g < nG; g += gridDim.x) {
        const int r0 = g << 3;
        if (r0 + 8 <= total_rows) {
            // fast path: 8 independent loads in flight, then 8 stores
            f4 v[8];
#pragma unroll
            for (int k = 0; k < 8; ++k) {
                const int rr = r0 + k;
                int corr = 0;   // b = 0 -> correction 0
#pragma unroll
                for (int i = 1; i < NB; ++i)
                    corr = (preA[i] <= rr) ? cA[i] : corr;
                v[k] = __builtin_nontemporal_load(
                           &x4[(size_t)(rr + corr) * F4 + tid]);
            }
#pragma unroll
            for (int k = 0; k < 8; ++k)
                __builtin_nontemporal_store(
                    v[k], &o4[(size_t)(r0 + k) * F4 + tid]);
        } else {
            // tail group
            for (int k = 0; k < 8; ++k) {
                const int rr = r0 + k;
                if (rr >= total_rows) break;
                int corr = 0;
#pragma unroll
                for (int i = 1; i < NB; ++i)
                    corr = (preA[i] <= rr) ? cA[i] : corr;
                o4[(size_t)rr * F4 + tid] = x4[(size_t)(rr + corr) * F4 + tid];
            }
        }
    }
}

// ---------------------------------------------------------------------------
// Generic fallback (any n_b <= 1024): LDS prefix + one row per block-iteration.
__global__ __launch_bounds__(256) void gather_generic(
        const float* __restrict__ x, const void* __restrict__ seq_raw,
        float* __restrict__ out, int n_b, int total_rows) {
    __shared__ int pre_s[1025];
    if (threadIdx.x == 0) {
        const int*       s32 = (const int*)seq_raw;
        const long long* s64 = (const long long*)seq_raw;
        long long sum32 = 0;
        for (int i = 0; i < n_b; ++i) sum32 += (long long)s32[i];
        const bool use32 = (sum32 == (long long)total_rows);
        int acc = 0;
        if (use32) {
            for (int i = 0; i < n_b; ++i) { pre_s[i] = acc; acc += s32[i]; }
        } else {
            for (int i = 0; i < n_b; ++i) { pre_s[i] = acc; acc += (int)s64[i]; }
        }
        pre_s[n_b] = acc;
    }
    __syncthreads();

    const f4* __restrict__ x4 = (const f4*)x;
    f4* __restrict__ o4       = (f4*)out;
    for (int r = blockIdx.x; r < total_rows; r += gridDim.x) {
        int b = 0;
        for (int i = 1; i < n_b; ++i) b += (pre_s[i] <= r) ? 1 : 0;
        const int t = r - pre_s[b];
        o4[(size_t)r * F4 + threadIdx.x] =
            x4[((size_t)b * TT + t) * F4 + threadIdx.x];
    }
}

// ---------------------------------------------------------------------------
extern "C" void kernel_launch(void* const* d_in, const int* in_sizes, int n_in,
                              void* d_out, int out_size, void* d_ws, size_t ws_size,
                              hipStream_t stream) {
    const float* x   = (const float*)d_in[0];
    const void*  seq = d_in[1];
    const int    n_b = in_sizes[1];
    float*       out = (float*)d_out;

    const int total_rows = out_size / DD;
    if (total_rows <= 0) return;

    if (n_b == NB) {
        const int nG = (total_rows + 7) >> 3;
        const int grid = nG < 2048 ? nG : 2048;
        gather16<<<grid, 256, 0, stream>>>(x, seq, out, total_rows);
    } else {
        const int grid = total_rows < 2048 ? total_rows : 2048;
        gather_generic<<<grid, 256, 0, stream>>>(x, seq, out, n_b, total_rows);
    }
}